// Round 4
// baseline (129.859 us; speedup 1.0000x reference)
//
#include <hip/hip_runtime.h>
#include <hip/hip_bf16.h>
#include <stdint.h>

typedef unsigned short u16;
typedef __attribute__((ext_vector_type(8))) short short8;   // 8 bf16 (4 VGPRs) MFMA A/B frag
typedef __attribute__((ext_vector_type(4))) float floatx4;  // MFMA C/D frag
typedef unsigned int __attribute__((ext_vector_type(2))) uint2v;

#define M_TOT 16384   // B*S
#define N_OUT 2304
#define KX    768
#define KL    128     // E*R
#define SCALING 2.0f

// prep-kernel block regions (256 thr/blk, 8 elems/thr for cvt).
// x-conversion is FUSED into gemm_h now (it touches every x element exactly
// once), so prep only handles W/A/bmr/gate: 7201 -> 1057 blocks.
#define WBLKS   864    // W: 2304*768/2048
#define ABLKS   48     // A: 128*768/2048
#define BMRBLKS 144    // bmr: 2304*128/2048
#define PREP_BLOCKS (WBLKS + ABLKS + BMRBLKS + 1)  // +1 gate block

__device__ __forceinline__ u16 f2b(float f) {
  union { __hip_bfloat16 h; u16 u; } c; c.h = __float2bfloat16(f); return c.u;
}
__device__ __forceinline__ float ldf(const void* p, long i, bool f32) {
  if (f32) return ((const float*)p)[i];
  union { u16 u; __hip_bfloat16 h; } c; c.u = ((const u16*)p)[i];
  return __bfloat162float(c.h);
}

__device__ __forceinline__ void gload_lds16(const void* g, void* l) {
  __builtin_amdgcn_global_load_lds(
      (const __attribute__((address_space(1))) void*)g,
      (__attribute__((address_space(3))) void*)l, 16, 0, 0);
}

// 8-element fp32/bf16 -> bf16 convert-copy, group index i
__device__ __forceinline__ void cvt8(const void* src, u16* dst, long i, bool f32) {
  u16 v[8];
  if (f32) {
    const float4* s = (const float4*)src;
    float4 a = s[i * 2], b = s[i * 2 + 1];
    v[0] = f2b(a.x); v[1] = f2b(a.y); v[2] = f2b(a.z); v[3] = f2b(a.w);
    v[4] = f2b(b.x); v[5] = f2b(b.y); v[6] = f2b(b.z); v[7] = f2b(b.w);
  } else {
    *(uint4*)v = ((const uint4*)src)[i];
  }
  ((uint4*)dst)[i] = *(uint4*)v;
}

// ---- prep: fused dtype-detect + cvt(W,A) + bmr build + gate softmax ----
__global__ __launch_bounds__(256) void prep_kernel(
    const void* __restrict__ x,  const void* __restrict__ W,
    const void* __restrict__ A,  const void* __restrict__ Bm,
    const void* __restrict__ z,  const void* __restrict__ Wg,
    const void* __restrict__ bg,
    u16* __restrict__ Wbf, u16* __restrict__ Abf,
    u16* __restrict__ bmr, float* __restrict__ gsc, int* __restrict__ flagp) {
  __shared__ int s_flag;
  const int tid = threadIdx.x;
  // block-local dtype detect: even u16s of fp32 N(0,1) data are uniform mantissa
  // bits -> bf16-exp>=160 w.p. ~0.375; genuine bf16 N(0,1) never. (R2-verified)
  if (tid < 64) {
    u16 v = ((const u16*)x)[tid * 2];
    int e = (v >> 7) & 0xFF;
    int huge = (e >= 160) ? 1 : 0;
    for (int off = 1; off < 64; off <<= 1) huge += __shfl_xor(huge, off, 64);
    if (tid == 0) s_flag = (huge >= 4) ? 1 : 0;
  }
  __syncthreads();
  const bool f32 = (s_flag != 0);

  int b = blockIdx.x;
  if (b < WBLKS) {
    cvt8(W, Wbf, (long)b * 256 + tid, f32);
  } else if (b < WBLKS + ABLKS) {
    cvt8(A, Abf, (long)(b - WBLKS) * 256 + tid, f32);
  } else if (b < WBLKS + ABLKS + BMRBLKS) {
    // Bm [E][2304][16] -> bmr [2304][128]
    long i0 = ((long)(b - WBLKS - ABLKS) * 256 + tid) * 8;
    u16 v[8];
#pragma unroll
    for (int j = 0; j < 8; ++j) {
      long idx = i0 + j;
      long o = idx >> 7, er = idx & 127;
      long e = er >> 4, r = er & 15;
      v[j] = f2b(ldf(Bm, (e * 2304 + o) * 16 + r, f32));
    }
    *(uint4*)&bmr[i0] = *(uint4*)v;
  } else {
    // gate: gsc[bb*8+e] = softmax_e(z[bb,:].Wg[e,:] + bg[e]) * SCALING
    if (tid == 0) *flagp = s_flag;
    if (tid < 64) {
      const int bb = tid >> 3, e = tid & 7;
      float acc = ldf(bg, e, f32);
      for (int i = 0; i < 64; ++i)
        acc += ldf(z, bb * 64 + i, f32) * ldf(Wg, e * 64 + i, f32);
      float mx = acc;
      for (int off = 1; off < 8; off <<= 1) mx = fmaxf(mx, __shfl_xor(mx, off, 64));
      float ex = __expf(acc - mx);
      float sm = ex;
      for (int off = 1; off < 8; off <<= 1) sm += __shfl_xor(sm, off, 64);
      gsc[tid] = (ex / sm) * SCALING;
    }
  }
}

// ---- gemm_h: hg[m, e*16+r] = (x @ A^T)[m,er] * gsc[batch(m)*8+e] ----
// M=16384, N=128, K=768; BM=64 tile, 256 blocks (all CUs busy).
// FUSED x-conversion: each block covers x rows [m0,m0+64) exactly once, so
// it reg-loads x (fp32 or bf16), converts, ds_writes As (XOR-swizzled: both
// write & read sides in-kernel, rule #21 ok) AND global-writes xbf for
// gemm_main. This removes prep's separate 75MB x pass.
__global__ __launch_bounds__(256) void gemm_h(
    const void* __restrict__ x, const u16* __restrict__ Abf,
    const float* __restrict__ gsc, u16* __restrict__ xbf,
    u16* __restrict__ hg, const int* __restrict__ flagp) {
  __shared__ __align__(128) u16 As[64][64];   // 8KB, XOR-swizzled 16B chunks
  __shared__ __align__(128) u16 Bs[128][64];  // 16KB, linear (gload_lds)
  const int tid = threadIdx.x, wave = tid >> 6, lane = tid & 63;
  const int wm = wave >> 1, wn = wave & 1;       // 2m x 2n waves, wave-tile 32x64
  const int quad = lane >> 4, l16 = lane & 15;
  const int srow = lane >> 3, scol = (lane & 7) * 8;
  const int m0 = blockIdx.x * 64;
  const bool f32 = (*flagp != 0);

  // x-stage assignment: row = tid>>2 (16 rows/wave -> coalesced 256B runs),
  // 16 consecutive cols at cg16 = (tid&3)*16.
  const int xr = tid >> 2, cg16 = (tid & 3) * 16;
  char* Asb = (char*)&As[0][0];

  floatx4 acc[2][4];
#pragma unroll
  for (int i = 0; i < 2; ++i)
#pragma unroll
    for (int j = 0; j < 4; ++j) acc[i][j] = floatx4{0.f, 0.f, 0.f, 0.f};

  for (int kb = 0; kb < 12; ++kb) {
    const int kc = kb * 64;
    // A: load x, convert, write LDS (swizzled) + xbf (linear)
    {
      const long off = (long)(m0 + xr) * KX + kc + cg16;
      uint4 lo, hi;
      if (f32) {
        const float4* xs = (const float4*)((const float*)x + off);
        float4 f0 = xs[0], f1 = xs[1], f2c = xs[2], f3 = xs[3];
        u16 v[16];
        v[0] = f2b(f0.x); v[1] = f2b(f0.y); v[2]  = f2b(f0.z); v[3]  = f2b(f0.w);
        v[4] = f2b(f1.x); v[5] = f2b(f1.y); v[6]  = f2b(f1.z); v[7]  = f2b(f1.w);
        v[8] = f2b(f2c.x); v[9] = f2b(f2c.y); v[10] = f2b(f2c.z); v[11] = f2b(f2c.w);
        v[12] = f2b(f3.x); v[13] = f2b(f3.y); v[14] = f2b(f3.z); v[15] = f2b(f3.w);
        lo = *(uint4*)&v[0]; hi = *(uint4*)&v[8];
      } else {
        lo = *(const uint4*)&((const u16*)x)[off];
        hi = *(const uint4*)&((const u16*)x)[off + 8];
      }
      *(uint4*)&xbf[off] = lo;
      *(uint4*)&xbf[off + 8] = hi;
      const int cb = cg16 * 2, sw = (xr & 7) << 4;
      *(uint4*)(Asb + xr * 128 + ((cb +  0) ^ sw)) = lo;
      *(uint4*)(Asb + xr * 128 + ((cb + 16) ^ sw)) = hi;
    }
    // B: 128 rows of Abf via gload_lds (linear)
#pragma unroll
    for (int j = 0; j < 4; ++j) {
      int r = wave * 32 + j * 8 + srow;
      gload_lds16(Abf + (size_t)r * KX + kc + scol,
                  (char*)(&Bs[0][0]) + (wave * 32 + j * 8) * 128);
    }
    __syncthreads();
#pragma unroll
    for (int ks = 0; ks < 2; ++ks) {
      short8 af[2], bf[4];
#pragma unroll
      for (int mi = 0; mi < 2; ++mi) {
        int ar = wm * 32 + mi * 16 + l16;
        af[mi] = *(const short8*)(Asb + ar * 128 + ((ks * 64 + quad * 16) ^ ((ar & 7) << 4)));
      }
#pragma unroll
      for (int ni = 0; ni < 4; ++ni)
        bf[ni] = *(const short8*)&Bs[wn * 64 + ni * 16 + l16][ks * 32 + quad * 8];
#pragma unroll
      for (int mi = 0; mi < 2; ++mi)
#pragma unroll
        for (int ni = 0; ni < 4; ++ni)
          acc[mi][ni] = __builtin_amdgcn_mfma_f32_16x16x32_bf16(af[mi], bf[ni], acc[mi][ni], 0, 0, 0);
    }
    __syncthreads();
  }
  // epilogue: scale by gate; e = col>>4 = wn*4+ni (col-block 16 = one expert)
  const int bb = m0 >> 11;
  float gv[4];
#pragma unroll
  for (int ni = 0; ni < 4; ++ni) gv[ni] = gsc[bb * 8 + wn * 4 + ni];
#pragma unroll
  for (int mi = 0; mi < 2; ++mi) {
    int rbase = m0 + wm * 32 + mi * 16 + quad * 4;
#pragma unroll
    for (int ni = 0; ni < 4; ++ni) {
      int c = wn * 64 + ni * 16 + l16;
#pragma unroll
      for (int t = 0; t < 4; ++t)
        hg[(size_t)(rbase + t) * KL + c] = f2b(acc[mi][ni][t] * gv[ni]);
    }
  }
}

// ---- gemm_main: out = [x | hg] @ [W | bmr]^T + b ; M=16384 N=2304 K=896 ----
// R3 structure (2-phase 128x128, 40KB pad -> 4 blocks/CU, supertile order).
// NEW: TRANSPOSED MFMA (swap operands -> D[n][m]): each lane owns 4
// CONSECUTIVE output columns of one row -> epilogue is 16 nontemporal
// dwordx4 stores instead of 64 scalar dwords (fixes the 209MB-vs-144MiB
// WRITE_SIZE partial-segment overhead). Products identical -> bit-exact.
__global__ __launch_bounds__(256) void gemm_main(
    const u16* __restrict__ xbf, const u16* __restrict__ hg,
    const u16* __restrict__ Wbf, const u16* __restrict__ bmr,
    const void* __restrict__ bias, void* __restrict__ outv,
    const int* __restrict__ flagp) {
  __shared__ __align__(128) u16 As[128][64];
  __shared__ __align__(128) u16 Bs[128][64];
  __shared__ u16 occ_pad[4096];   // 8KB: LDS 32->40KB caps blocks/CU at 4
  const int tid = threadIdx.x, wave = tid >> 6, lane = tid & 63;
  const int wm = wave >> 1, wn = wave & 1;
  const int quad = lane >> 4, l16 = lane & 15;
  const int srow = lane >> 3, scol = (lane & 7) * 8;

  // XCD swizzle + supertile order: 2304 blocks = 8 xcd * 288.
  // Per XCD: 16 m-tiles (= one batch) x 18 n-tiles; ST = 8m x 3n, m-fastest.
  const int linear = blockIdx.x;
  const int xcd = linear & 7;
  const int g = linear >> 3;            // 0..287
  const int st = g / 24;                // 0..11: st_n = st%6, st_m = st/6
  const int w  = g % 24;
  const int m_idx = xcd * 16 + (st / 6) * 8 + (w & 7);
  const int n_idx = (st % 6) * 3 + (w >> 3);
  const int m0 = m_idx * 128;
  const int n0 = n_idx * 128;
  if (tid == 0) ((volatile u16*)occ_pad)[0] = (u16)linear;  // keep pad alive

  floatx4 acc[4][4];
#pragma unroll
  for (int i = 0; i < 4; ++i)
#pragma unroll
    for (int j = 0; j < 4; ++j) acc[i][j] = floatx4{0.f, 0.f, 0.f, 0.f};

  for (int kb = 0; kb < 14; ++kb) {
    const u16* ap; const u16* bp; int lda, ldb, kc;
    if (kb < 12) { ap = xbf; lda = KX; bp = Wbf; ldb = KX; kc = kb * 64; }
    else         { ap = hg;  lda = KL; bp = bmr; ldb = KL; kc = (kb - 12) * 64; }
#pragma unroll
    for (int j = 0; j < 4; ++j) {
      int r = wave * 32 + j * 8 + srow;
      gload_lds16(ap + (size_t)(m0 + r) * lda + kc + scol,
                  (char*)(&As[0][0]) + (wave * 32 + j * 8) * 128);
      gload_lds16(bp + (size_t)(n0 + r) * ldb + kc + scol,
                  (char*)(&Bs[0][0]) + (wave * 32 + j * 8) * 128);
    }
    __syncthreads();
#pragma unroll
    for (int ks = 0; ks < 2; ++ks) {
      short8 af[4], bf[4];
#pragma unroll
      for (int mi = 0; mi < 4; ++mi)
        af[mi] = *(const short8*)&As[wm * 64 + mi * 16 + l16][ks * 32 + quad * 8];
#pragma unroll
      for (int ni = 0; ni < 4; ++ni)
        bf[ni] = *(const short8*)&Bs[wn * 64 + ni * 16 + l16][ks * 32 + quad * 8];
      // TRANSPOSED: mfma(B,A) -> D[n-idx: quad*4+t][m-idx: l16]
#pragma unroll
      for (int mi = 0; mi < 4; ++mi)
#pragma unroll
        for (int ni = 0; ni < 4; ++ni)
          acc[mi][ni] = __builtin_amdgcn_mfma_f32_16x16x32_bf16(bf[ni], af[mi], acc[mi][ni], 0, 0, 0);
    }
    __syncthreads();
  }

  // epilogue (transposed layout): thread owns out row = m0+wm*64+mi*16+l16,
  // cols c0..c0+3 with c0 = n0+wn*64+ni*16+quad*4 -> one dwordx4 per frag.
  const bool f32 = (*flagp != 0);
#pragma unroll
  for (int mi = 0; mi < 4; ++mi) {
    const size_t row = (size_t)(m0 + wm * 64 + mi * 16 + l16);
#pragma unroll
    for (int ni = 0; ni < 4; ++ni) {
      const int c0 = n0 + wn * 64 + ni * 16 + quad * 4;
      float b0, b1, b2, b3;
      if (f32) {
        const float4 bv = *(const float4*)((const float*)bias + c0);
        b0 = bv.x; b1 = bv.y; b2 = bv.z; b3 = bv.w;
      } else {
        b0 = ldf(bias, c0, false);     b1 = ldf(bias, c0 + 1, false);
        b2 = ldf(bias, c0 + 2, false); b3 = ldf(bias, c0 + 3, false);
      }
      const float v0 = acc[mi][ni][0] + b0, v1 = acc[mi][ni][1] + b1;
      const float v2 = acc[mi][ni][2] + b2, v3 = acc[mi][ni][3] + b3;
      if (f32) {
        floatx4 v = {v0, v1, v2, v3};
        __builtin_nontemporal_store(
            v, (floatx4*)((float*)outv + row * N_OUT + c0));
      } else {
        union { u16 h[4]; uint2v u; } pk;
        pk.h[0] = f2b(v0); pk.h[1] = f2b(v1); pk.h[2] = f2b(v2); pk.h[3] = f2b(v3);
        __builtin_nontemporal_store(
            pk.u, (uint2v*)((u16*)outv + row * N_OUT + c0));
      }
    }
  }
}

extern "C" void kernel_launch(void* const* d_in, const int* in_sizes, int n_in,
                              void* d_out, int out_size, void* d_ws, size_t ws_size,
                              hipStream_t stream) {
  // setup order: x, z, W, b, A, Bm, Wg, bg
  const void* x  = d_in[0];
  const void* z  = d_in[1];
  const void* W  = d_in[2];
  const void* bb = d_in[3];
  const void* A  = d_in[4];
  const void* Bm = d_in[5];
  const void* Wg = d_in[6];
  const void* bg = d_in[7];

  char* ws = (char*)d_ws;
  int*   flag = (int*)ws;
  float* gsc  = (float*)(ws + 256);
  u16*   xbf  = (u16*)(ws + 1024);                                   // 16384*768
  u16*   Wbf  = (u16*)(ws + 1024 + 25165824ull);                     // 2304*768
  u16*   Abf  = (u16*)(ws + 1024 + 25165824ull + 3538944ull);        // 128*768
  u16*   bmr  = (u16*)(ws + 1024 + 25165824ull + 3538944ull + 196608ull);
  u16*   hg   = (u16*)(ws + 1024 + 25165824ull + 3538944ull + 196608ull + 589824ull);

  prep_kernel<<<PREP_BLOCKS, 256, 0, stream>>>(
      x, W, A, Bm, z, Wg, bg, Wbf, Abf, bmr, gsc, flag);

  gemm_h<<<M_TOT / 64, 256, 0, stream>>>(x, Abf, gsc, xbf, hg, flag);

  gemm_main<<<(N_OUT / 128) * (M_TOT / 128), 256, 0, stream>>>(
      xbf, hg, Wbf, bmr, bb, d_out, flag);
}

// Round 5
// 124.647 us; speedup vs baseline: 1.0418x; 1.0418x over previous
//
#include <hip/hip_runtime.h>
#include <hip/hip_bf16.h>
#include <stdint.h>

typedef unsigned short u16;
typedef __attribute__((ext_vector_type(8))) short short8;   // 8 bf16 (4 VGPRs) MFMA A/B frag
typedef __attribute__((ext_vector_type(4))) float floatx4;  // MFMA C/D frag

#define M_TOT 16384   // B*S
#define N_OUT 2304
#define KX    768
#define KL    128     // E*R
#define SCALING 2.0f

// conversion block regions (256 thr/blk, 8 elems/thr)
#define WBLKS   864    // W: 2304*768/2048
#define ABLKS   48     // A: 128*768/2048
#define BMRBLKS 144    // bmr: 2304*128/2048
#define GH_BLOCKS 256  // gemm_h: M_TOT/64

__device__ __forceinline__ u16 f2b(float f) {
  union { __hip_bfloat16 h; u16 u; } c; c.h = __float2bfloat16(f); return c.u;
}
__device__ __forceinline__ float ldf(const void* p, long i, bool f32) {
  if (f32) return ((const float*)p)[i];
  union { u16 u; __hip_bfloat16 h; } c; c.u = ((const u16*)p)[i];
  return __bfloat162float(c.h);
}

__device__ __forceinline__ void gload_lds16(const void* g, void* l) {
  __builtin_amdgcn_global_load_lds(
      (const __attribute__((address_space(1))) void*)g,
      (__attribute__((address_space(3))) void*)l, 16, 0, 0);
}

// 8-element fp32/bf16 -> bf16 convert-copy, group index i
__device__ __forceinline__ void cvt8(const void* src, u16* dst, long i, bool f32) {
  u16 v[8];
  if (f32) {
    const float4* s = (const float4*)src;
    float4 a = s[i * 2], b = s[i * 2 + 1];
    v[0] = f2b(a.x); v[1] = f2b(a.y); v[2] = f2b(a.z); v[3] = f2b(a.w);
    v[4] = f2b(b.x); v[5] = f2b(b.y); v[6] = f2b(b.z); v[7] = f2b(b.w);
  } else {
    *(uint4*)v = ((const uint4*)src)[i];
  }
  ((uint4*)dst)[i] = *(uint4*)v;
}

// ---- prep_small: dtype-detect + A convert + gate softmax + flag ----
// Tiny (49 blocks): only what gemm_h depends on. W/bmr conversion is merged
// into the gemm_h launch (no dependency) so it overlaps gemm_h's compute.
__global__ __launch_bounds__(256) void prep_small(
    const void* __restrict__ x,  const void* __restrict__ A,
    const void* __restrict__ z,  const void* __restrict__ Wg,
    const void* __restrict__ bg,
    u16* __restrict__ Abf, float* __restrict__ gsc, int* __restrict__ flagp) {
  __shared__ int s_flag;
  const int tid = threadIdx.x;
  // block-local dtype detect: even u16s of fp32 N(0,1) data are uniform mantissa
  // bits -> bf16-exp>=160 w.p. ~0.375; genuine bf16 N(0,1) never. (R2-verified)
  if (tid < 64) {
    u16 v = ((const u16*)x)[tid * 2];
    int e = (v >> 7) & 0xFF;
    int huge = (e >= 160) ? 1 : 0;
    for (int off = 1; off < 64; off <<= 1) huge += __shfl_xor(huge, off, 64);
    if (tid == 0) s_flag = (huge >= 4) ? 1 : 0;
  }
  __syncthreads();
  const bool f32 = (s_flag != 0);

  int b = blockIdx.x;
  if (b < ABLKS) {
    cvt8(A, Abf, (long)b * 256 + tid, f32);
  } else {
    // gate: gsc[bb*8+e] = softmax_e(z[bb,:].Wg[e,:] + bg[e]) * SCALING
    if (tid == 0) *flagp = s_flag;
    if (tid < 64) {
      const int bb = tid >> 3, e = tid & 7;
      float acc = ldf(bg, e, f32);
      for (int i = 0; i < 64; ++i)
        acc += ldf(z, bb * 64 + i, f32) * ldf(Wg, e * 64 + i, f32);
      float mx = acc;
      for (int off = 1; off < 8; off <<= 1) mx = fmaxf(mx, __shfl_xor(mx, off, 64));
      float ex = __expf(acc - mx);
      float sm = ex;
      for (int off = 1; off < 8; off <<= 1) sm += __shfl_xor(sm, off, 64);
      gsc[tid] = (ex / sm) * SCALING;
    }
  }
}

// ---- fused gemm_h + W/bmr conversion ----
// blocks [0,256): gemm_h — hg[m, e*16+r] = (x @ A^T)[m,er] * gsc[batch*8+e],
//   M=16384 N=128 K=768, BM=64 tile, FUSED x fp32->bf16 conversion (writes
//   xbf as byproduct; removes the separate 75MB x pass). (R4-proven)
// blocks [256,1264): W convert + bmr build — independent of gemm_h, runs
//   concurrently under its MFMA work (saves a serialized launch).
__global__ __launch_bounds__(256) void gemm_h_fused(
    const void* __restrict__ x, const void* __restrict__ W,
    const void* __restrict__ Bm, const u16* __restrict__ Abf,
    const float* __restrict__ gsc, const int* __restrict__ flagp,
    u16* __restrict__ xbf, u16* __restrict__ Wbf, u16* __restrict__ bmr,
    u16* __restrict__ hg) {
  __shared__ __align__(128) u16 As[64][64];   // 8KB, XOR-swizzled 16B chunks
  __shared__ __align__(128) u16 Bs[128][64];  // 16KB, linear (gload_lds)
  const int tid = threadIdx.x;
  const bool f32 = (*flagp != 0);

  if (blockIdx.x >= GH_BLOCKS) {
    // ---- conversion region ----
    int c = blockIdx.x - GH_BLOCKS;
    if (c < WBLKS) {
      cvt8(W, Wbf, (long)c * 256 + tid, f32);
    } else {
      // Bm [E][2304][16] -> bmr [2304][128]
      long i0 = ((long)(c - WBLKS) * 256 + tid) * 8;
      u16 v[8];
#pragma unroll
      for (int j = 0; j < 8; ++j) {
        long idx = i0 + j;
        long o = idx >> 7, er = idx & 127;
        long e = er >> 4, r = er & 15;
        v[j] = f2b(ldf(Bm, (e * 2304 + o) * 16 + r, f32));
      }
      *(uint4*)&bmr[i0] = *(uint4*)v;
    }
    return;
  }

  // ---- gemm_h region ----
  const int wave = tid >> 6, lane = tid & 63;
  const int wm = wave >> 1, wn = wave & 1;       // 2m x 2n waves, wave-tile 32x64
  const int quad = lane >> 4, l16 = lane & 15;
  const int srow = lane >> 3, scol = (lane & 7) * 8;
  const int m0 = blockIdx.x * 64;

  // x-stage assignment: row = tid>>2 (16 rows/wave -> coalesced 256B runs),
  // 16 consecutive cols at cg16 = (tid&3)*16.
  const int xr = tid >> 2, cg16 = (tid & 3) * 16;
  char* Asb = (char*)&As[0][0];

  floatx4 acc[2][4];
#pragma unroll
  for (int i = 0; i < 2; ++i)
#pragma unroll
    for (int j = 0; j < 4; ++j) acc[i][j] = floatx4{0.f, 0.f, 0.f, 0.f};

  for (int kb = 0; kb < 12; ++kb) {
    const int kc = kb * 64;
    // A: load x, convert, write LDS (swizzled) + xbf (linear)
    {
      const long off = (long)(m0 + xr) * KX + kc + cg16;
      uint4 lo, hi;
      if (f32) {
        const float4* xs = (const float4*)((const float*)x + off);
        float4 f0 = xs[0], f1 = xs[1], f2c = xs[2], f3 = xs[3];
        u16 v[16];
        v[0] = f2b(f0.x); v[1] = f2b(f0.y); v[2]  = f2b(f0.z); v[3]  = f2b(f0.w);
        v[4] = f2b(f1.x); v[5] = f2b(f1.y); v[6]  = f2b(f1.z); v[7]  = f2b(f1.w);
        v[8] = f2b(f2c.x); v[9] = f2b(f2c.y); v[10] = f2b(f2c.z); v[11] = f2b(f2c.w);
        v[12] = f2b(f3.x); v[13] = f2b(f3.y); v[14] = f2b(f3.z); v[15] = f2b(f3.w);
        lo = *(uint4*)&v[0]; hi = *(uint4*)&v[8];
      } else {
        lo = *(const uint4*)&((const u16*)x)[off];
        hi = *(const uint4*)&((const u16*)x)[off + 8];
      }
      *(uint4*)&xbf[off] = lo;
      *(uint4*)&xbf[off + 8] = hi;
      const int cb = cg16 * 2, sw = (xr & 7) << 4;
      *(uint4*)(Asb + xr * 128 + ((cb +  0) ^ sw)) = lo;
      *(uint4*)(Asb + xr * 128 + ((cb + 16) ^ sw)) = hi;
    }
    // B: 128 rows of Abf via gload_lds (linear)
#pragma unroll
    for (int j = 0; j < 4; ++j) {
      int r = wave * 32 + j * 8 + srow;
      gload_lds16(Abf + (size_t)r * KX + kc + scol,
                  (char*)(&Bs[0][0]) + (wave * 32 + j * 8) * 128);
    }
    __syncthreads();
#pragma unroll
    for (int ks = 0; ks < 2; ++ks) {
      short8 af[2], bf[4];
#pragma unroll
      for (int mi = 0; mi < 2; ++mi) {
        int ar = wm * 32 + mi * 16 + l16;
        af[mi] = *(const short8*)(Asb + ar * 128 + ((ks * 64 + quad * 16) ^ ((ar & 7) << 4)));
      }
#pragma unroll
      for (int ni = 0; ni < 4; ++ni)
        bf[ni] = *(const short8*)&Bs[wn * 64 + ni * 16 + l16][ks * 32 + quad * 8];
#pragma unroll
      for (int mi = 0; mi < 2; ++mi)
#pragma unroll
        for (int ni = 0; ni < 4; ++ni)
          acc[mi][ni] = __builtin_amdgcn_mfma_f32_16x16x32_bf16(af[mi], bf[ni], acc[mi][ni], 0, 0, 0);
    }
    __syncthreads();
  }
  // epilogue: scale by gate; e = col>>4 = wn*4+ni (col-block 16 = one expert)
  const int bb = m0 >> 11;
  float gv[4];
#pragma unroll
  for (int ni = 0; ni < 4; ++ni) gv[ni] = gsc[bb * 8 + wn * 4 + ni];
#pragma unroll
  for (int mi = 0; mi < 2; ++mi) {
    int rbase = m0 + wm * 32 + mi * 16 + quad * 4;
#pragma unroll
    for (int ni = 0; ni < 4; ++ni) {
      int c = wn * 64 + ni * 16 + l16;
#pragma unroll
      for (int t = 0; t < 4; ++t)
        hg[(size_t)(rbase + t) * KL + c] = f2b(acc[mi][ni][t] * gv[ni]);
    }
  }
}

// ---- gemm_main: out = [x | hg] @ [W | bmr]^T + b ; M=16384 N=2304 K=896 ----
// EXACT R3 body (best measured: 104.9us, MfmaUtil 27.7): 2-phase 128x128,
// 40KB LDS pad -> 4 blocks/CU, XCD swizzle (xcd==batch) + 8m x 3n supertile.
// R4's transposed-MFMA epilogue experiment REVERTED (it regressed 105->111
// despite -15MB WRITE; write overhead is not on the critical path).
__global__ __launch_bounds__(256) void gemm_main(
    const u16* __restrict__ xbf, const u16* __restrict__ hg,
    const u16* __restrict__ Wbf, const u16* __restrict__ bmr,
    const void* __restrict__ bias, void* __restrict__ outv,
    const int* __restrict__ flagp) {
  __shared__ __align__(128) u16 As[128][64];
  __shared__ __align__(128) u16 Bs[128][64];
  __shared__ u16 occ_pad[4096];   // 8KB: LDS 32->40KB caps blocks/CU at 4
  const int tid = threadIdx.x, wave = tid >> 6, lane = tid & 63;
  const int wm = wave >> 1, wn = wave & 1;
  const int quad = lane >> 4, l16 = lane & 15;
  const int srow = lane >> 3, scol = (lane & 7) * 8;

  // XCD swizzle + supertile order: 2304 blocks = 8 xcd * 288.
  // Per XCD: 16 m-tiles (= one batch) x 18 n-tiles; ST = 8m x 3n, m-fastest.
  const int linear = blockIdx.x;
  const int xcd = linear & 7;
  const int g = linear >> 3;            // 0..287
  const int st = g / 24;                // 0..11: st_n = st%6, st_m = st/6
  const int w  = g % 24;
  const int m_idx = xcd * 16 + (st / 6) * 8 + (w & 7);
  const int n_idx = (st % 6) * 3 + (w >> 3);
  const int m0 = m_idx * 128;
  const int n0 = n_idx * 128;
  if (tid == 0) ((volatile u16*)occ_pad)[0] = (u16)linear;  // keep pad alive

  floatx4 acc[4][4];
#pragma unroll
  for (int i = 0; i < 4; ++i)
#pragma unroll
    for (int j = 0; j < 4; ++j) acc[i][j] = floatx4{0.f, 0.f, 0.f, 0.f};

  for (int kb = 0; kb < 14; ++kb) {
    const u16* ap; const u16* bp; int lda, ldb, kc;
    if (kb < 12) { ap = xbf; lda = KX; bp = Wbf; ldb = KX; kc = kb * 64; }
    else         { ap = hg;  lda = KL; bp = bmr; ldb = KL; kc = (kb - 12) * 64; }
#pragma unroll
    for (int j = 0; j < 4; ++j) {
      int r = wave * 32 + j * 8 + srow;
      gload_lds16(ap + (size_t)(m0 + r) * lda + kc + scol,
                  (char*)(&As[0][0]) + (wave * 32 + j * 8) * 128);
      gload_lds16(bp + (size_t)(n0 + r) * ldb + kc + scol,
                  (char*)(&Bs[0][0]) + (wave * 32 + j * 8) * 128);
    }
    __syncthreads();
#pragma unroll
    for (int ks = 0; ks < 2; ++ks) {
      short8 af[4], bf[4];
#pragma unroll
      for (int mi = 0; mi < 4; ++mi)
        af[mi] = *(const short8*)&As[wm * 64 + mi * 16 + l16][ks * 32 + quad * 8];
#pragma unroll
      for (int ni = 0; ni < 4; ++ni)
        bf[ni] = *(const short8*)&Bs[wn * 64 + ni * 16 + l16][ks * 32 + quad * 8];
#pragma unroll
      for (int mi = 0; mi < 4; ++mi)
#pragma unroll
        for (int ni = 0; ni < 4; ++ni)
          acc[mi][ni] = __builtin_amdgcn_mfma_f32_16x16x32_bf16(af[mi], bf[ni], acc[mi][ni], 0, 0, 0);
    }
    __syncthreads();
  }

  // epilogue: C/D row = quad*4+t, col = l16 (m89/m91). Nontemporal stores:
  // output is write-once, never re-read -> avoid read-for-ownership fetch.
  const bool f32 = (*flagp != 0);
  float bv[4];
#pragma unroll
  for (int ni = 0; ni < 4; ++ni)
    bv[ni] = ldf(bias, n0 + wn * 64 + ni * 16 + l16, f32);
#pragma unroll
  for (int mi = 0; mi < 4; ++mi) {
    int rbase = m0 + wm * 64 + mi * 16 + quad * 4;
#pragma unroll
    for (int ni = 0; ni < 4; ++ni) {
      int c = n0 + wn * 64 + ni * 16 + l16;
#pragma unroll
      for (int t = 0; t < 4; ++t) {
        float v = acc[mi][ni][t] + bv[ni];
        size_t idx = (size_t)(rbase + t) * N_OUT + c;
        if (f32) __builtin_nontemporal_store(v, (float*)outv + idx);
        else     __builtin_nontemporal_store(f2b(v), (u16*)outv + idx);
      }
    }
  }
}

extern "C" void kernel_launch(void* const* d_in, const int* in_sizes, int n_in,
                              void* d_out, int out_size, void* d_ws, size_t ws_size,
                              hipStream_t stream) {
  // setup order: x, z, W, b, A, Bm, Wg, bg
  const void* x  = d_in[0];
  const void* z  = d_in[1];
  const void* W  = d_in[2];
  const void* bb = d_in[3];
  const void* A  = d_in[4];
  const void* Bm = d_in[5];
  const void* Wg = d_in[6];
  const void* bg = d_in[7];

  char* ws = (char*)d_ws;
  int*   flag = (int*)ws;
  float* gsc  = (float*)(ws + 256);
  u16*   xbf  = (u16*)(ws + 1024);                                   // 16384*768
  u16*   Wbf  = (u16*)(ws + 1024 + 25165824ull);                     // 2304*768
  u16*   Abf  = (u16*)(ws + 1024 + 25165824ull + 3538944ull);        // 128*768
  u16*   bmr  = (u16*)(ws + 1024 + 25165824ull + 3538944ull + 196608ull);
  u16*   hg   = (u16*)(ws + 1024 + 25165824ull + 3538944ull + 196608ull + 589824ull);

  prep_small<<<ABLKS + 1, 256, 0, stream>>>(x, A, z, Wg, bg, Abf, gsc, flag);

  gemm_h_fused<<<GH_BLOCKS + WBLKS + BMRBLKS, 256, 0, stream>>>(
      x, W, Bm, Abf, gsc, flag, xbf, Wbf, bmr, hg);

  gemm_main<<<(N_OUT / 128) * (M_TOT / 128), 256, 0, stream>>>(
      xbf, hg, Wbf, bmr, bb, d_out, flag);
}